// Round 14
// baseline (88.604 us; speedup 1.0000x reference)
//
#include <hip/hip_runtime.h>
#include <hip/hip_bf16.h>
#include <math.h>

#define NF 64
#define NC 16
#define HC 8                           // comps per half-block
#define MAIN_GROUPS 256                // tile groups; blocks = 2*groups
#define MAIN_WAVES  13                 // 832 thr; 3328 tile-slots vs 3125 tiles
#define TPW 4                          // 16-sample subtiles per wave (64 samples)

typedef __bf16 bf16x8 __attribute__((ext_vector_type(8)));
typedef float f32x4 __attribute__((ext_vector_type(4)));
typedef unsigned int u32;

// async global->LDS, 16B/lane. LDS dest = wave-uniform base (HW adds lane*16).
__device__ __forceinline__ void stage16(const void* gsrc, void* ldst) {
    __builtin_amdgcn_global_load_lds(
        (const __attribute__((address_space(1))) u32*)gsrc,
        (__attribute__((address_space(3))) u32*)ldst,
        16, 0, 0);
}

// VALU-pipe cross-lane reductions (permlane swaps; not on the lgkm queue).
__device__ __forceinline__ float xor32_sum(float x) {
    float a = x, b = x;
    asm("v_permlane32_swap_b32 %0, %1" : "+v"(a), "+v"(b));
    return a + b;
}
__device__ __forceinline__ float xor16_sum(float x) {
    float a = x, b = x;
    asm("v_permlane16_swap_b32 %0, %1" : "+v"(a), "+v"(b));
    return a + b;
}

// ---------------------------------------------------------------------------
// Kernel 1 v8 (unchanged): 4-wave cooperative Cholesky + inverse, rolled
// phase loops (L1I-resident ~13KB). See round-8 notes.
// ---------------------------------------------------------------------------
__global__ __launch_bounds__(256) void gmm_precompute(
    const float* __restrict__ cov,
    const float* __restrict__ means,
    const float* __restrict__ weights,
    __hip_bfloat16* __restrict__ g,
    float* __restrict__ t,
    float* __restrict__ Cc)
{
    const int w = threadIdx.x >> 6;   // wave 0..3: rows [16w,16w+16)
    const int c = threadIdx.x & 63;   // lane owns column c
    const int k = blockIdx.x;

    __shared__ __align__(16) float LT[NF][68];   // LT[j][r] = L[r][j]
    __shared__ float Xs[NF][65];                 // Xs[i][c] = G[i][c]
    __shared__ __align__(16) float wb2[2][68];   // ping-pong published row
    __shared__ __align__(16) float gw2[2][68];   // ping-pong published G row

    float a_loc[16];
    {
        const float* src = cov + (long)k * NF * NF + (w * 16) * NF + c;
        #pragma unroll
        for (int r = 0; r < 16; ++r)
            a_loc[r] = src[r * NF];
    }

    float rsq_loc[16];
    float logdiag = 0.0f;

    #pragma unroll 1
    for (int q = 0; q < 4; ++q) {
        #pragma unroll
        for (int jj = 0; jj < 16; ++jj) {
            float* wb = wb2[jj & 1];
            if (w == q) wb[c] = a_loc[jj];       // publish trailing row j
            __syncthreads();
            const int j = q * 16 + jj;
            float ajc = wb[c];
            float d   = wb[j];
            float sq  = sqrtf(d);
            float rsq = __builtin_amdgcn_rcpf(sq);
            float rd  = __builtin_amdgcn_rcpf(d);
            logdiag += 0.5f * __logf(d);
            if (w == q) rsq_loc[jj] = rsq;
            LT[j][c] = ajc * rsq;
            float beta = ajc * rd;
            const float4* wv = (const float4*)(wb + w * 16);
            #pragma unroll
            for (int rr = 0; rr < 16; rr += 4) {
                float4 v = wv[rr >> 2];
                a_loc[rr]     = fmaf(-v.x, beta, a_loc[rr]);
                a_loc[rr + 1] = fmaf(-v.y, beta, a_loc[rr + 1]);
                a_loc[rr + 2] = fmaf(-v.z, beta, a_loc[rr + 2]);
                a_loc[rr + 3] = fmaf(-v.w, beta, a_loc[rr + 3]);
            }
        }
    }

    float s_loc[16];
    #pragma unroll
    for (int r = 0; r < 16; ++r)
        s_loc[r] = (w * 16 + r == c) ? 1.0f : 0.0f;

    #pragma unroll 1
    for (int q = 0; q < 4; ++q) {
        #pragma unroll
        for (int ii = 0; ii < 16; ++ii) {
            const int i = q * 16 + ii;
            float* gw = gw2[ii & 1];
            if (w == q) {
                float gv = s_loc[ii] * rsq_loc[ii];
                gw[c] = gv;
                Xs[i][c] = gv;
            }
            __syncthreads();
            float gc = gw[c];
            const float4* lv4 = (const float4*)(&LT[i][w * 16]);
            #pragma unroll
            for (int rr = 0; rr < 16; rr += 4) {
                float4 v = lv4[rr >> 2];
                s_loc[rr]     = fmaf(-v.x, gc, s_loc[rr]);
                s_loc[rr + 1] = fmaf(-v.y, gc, s_loc[rr + 1]);
                s_loc[rr + 2] = fmaf(-v.z, gc, s_loc[rr + 2]);
                s_loc[rr + 3] = fmaf(-v.w, gc, s_loc[rr + 3]);
            }
        }
    }
    __syncthreads();

    // g row c: chunks jb=2w,2w+1, XOR-swizzled (jb ^ (row&7))
    {
        __hip_bfloat16* grow = g + ((long)(k * NF + c)) * NF;
        #pragma unroll
        for (int h = 0; h < 2; ++h) {
            int jb = w * 2 + h;
            bf16x8 v;
            #pragma unroll
            for (int u = 0; u < 8; ++u)
                v[u] = (__bf16)Xs[c][jb * 8 + u];
            *(bf16x8*)(grow + ((jb ^ (c & 7)) * 8)) = v;
        }
    }

    if (w == 0) {
        const float* mu = means + k * NF;
        float a0 = 0.0f, a1 = 0.0f;
        #pragma unroll
        for (int j = 0; j < NF; j += 2) {
            a0 = fmaf(Xs[c][j],     mu[j],     a0);
            a1 = fmaf(Xs[c][j + 1], mu[j + 1], a1);
        }
        t[k * NF + c] = a0 + a1;
        if (c == 0)
            Cc[k] = __logf(weights[k]) - 0.5f * (float)NF * 1.8378770664093453f - logdiag;
    }
}

// ---------------------------------------------------------------------------
// Kernel 2 v14: COMPONENT-SPLIT for 2 blocks/CU. Block (grp,half) stages 8
// comps (64KB G + 2KB nt = 66KB LDS -> two blocks co-reside per CU: 26
// waves/CU = 6.5/SIMD, double v13's TLP; per-CU DS/VALU/MFMA totals are
// unchanged). Each wave computes the per-sample HALF-logsumexp over its 8
// comps and writes m+log(s) to lseP[half]; gmm_partial merges (exact:
// logsumexp is associative). Triangular skip + stagger + 0-conflict swizzle
// kept. VGPR must stay <=64 (v13 measured 52) -> launch_bounds(832,7).
// ---------------------------------------------------------------------------
__global__ __launch_bounds__(832, 7) void gmm_main(
    const float* __restrict__ data,
    const char* __restrict__ gsw,         // swizzled bf16 G, [NC][8192 B]
    const float* __restrict__ t,
    const float* __restrict__ Cc,
    float* __restrict__ lseP,             // [2][nTiles*64] half-LSE
    int nTiles, int N, int totalWaves)
{
    __shared__ __align__(16) char gbuf[HC * 8192];   // 64 KiB
    __shared__ __align__(16) float nt_lds[HC * NF];  // 2 KiB
    __shared__ float cc_lds[HC];

    const int tidx = threadIdx.x;
    const int w    = tidx >> 6;
    const int lane = tidx & 63;
    const int l15  = lane & 15;
    const int lg   = lane >> 4;
    const int half = blockIdx.x & 1;
    const int grp  = blockIdx.x >> 1;

    // waves 0..7 stage one comp each (half*8 + w)
    if (w < HC) {
        const char* src = gsw + (size_t)(half * HC + w) * 8192;
        char* dst = gbuf + (size_t)w * 8192;
        #pragma unroll
        for (int u = 0; u < 8; ++u)
            stage16(src + u * 1024 + lane * 16, dst + u * 1024);
    }
    for (int i = tidx; i < HC * NF; i += 64 * MAIN_WAVES)
        nt_lds[i] = -t[half * HC * NF + i];
    if (tidx < HC) cc_lds[tidx] = Cc[half * HC + tidx];

    const int gid = grp * MAIN_WAVES + w;

    // swizzled LDS byte offsets (static per lane)
    int offA[4], offB[4];
    #pragma unroll
    for (int rc = 0; rc < 4; ++rc) {
        int row = rc * 16 + l15;
        offA[rc] = row * 128 + ((lg       ^ (l15 & 7)) * 16);
        offB[rc] = row * 128 + (((lg + 4) ^ (l15 & 7)) * 16);
    }

    // first tile's x fragments (overlaps the staging flight)
    bf16x8 xf[TPW][2];
    if (gid < nTiles) {
        const long base = (long)gid * (TPW * 16);
        #pragma unroll
        for (int st = 0; st < TPW; ++st) {
            long row = base + st * 16 + l15;
            if (row > (long)N - 1) row = (long)N - 1;
            const float* xp = data + row * NF + lg * 8;
            float4 a0 = *(const float4*)(xp);
            float4 a1 = *(const float4*)(xp + 4);
            float4 b0 = *(const float4*)(xp + 32);
            float4 b1 = *(const float4*)(xp + 36);
            bf16x8 f0, f1;
            f0[0] = (__bf16)a0.x; f0[1] = (__bf16)a0.y;
            f0[2] = (__bf16)a0.z; f0[3] = (__bf16)a0.w;
            f0[4] = (__bf16)a1.x; f0[5] = (__bf16)a1.y;
            f0[6] = (__bf16)a1.z; f0[7] = (__bf16)a1.w;
            f1[0] = (__bf16)b0.x; f1[1] = (__bf16)b0.y;
            f1[2] = (__bf16)b0.z; f1[3] = (__bf16)b0.w;
            f1[4] = (__bf16)b1.x; f1[5] = (__bf16)b1.y;
            f1[6] = (__bf16)b1.z; f1[7] = (__bf16)b1.w;
            xf[st][0] = f0;
            xf[st][1] = f1;
        }
    }

    __syncthreads();   // G + t staged; only barrier in the kernel

    #pragma unroll 1
    for (int tile = gid; tile < nTiles; tile += totalWaves) {
        const long base = (long)tile * (TPW * 16);
        if (tile != gid) {     // grid-stride continuation (cold path)
            #pragma unroll
            for (int st = 0; st < TPW; ++st) {
                long row = base + st * 16 + l15;
                if (row > (long)N - 1) row = (long)N - 1;
                const float* xp = data + row * NF + lg * 8;
                float4 a0 = *(const float4*)(xp);
                float4 a1 = *(const float4*)(xp + 4);
                float4 b0 = *(const float4*)(xp + 32);
                float4 b1 = *(const float4*)(xp + 36);
                bf16x8 f0, f1;
                f0[0] = (__bf16)a0.x; f0[1] = (__bf16)a0.y;
                f0[2] = (__bf16)a0.z; f0[3] = (__bf16)a0.w;
                f0[4] = (__bf16)a1.x; f0[5] = (__bf16)a1.y;
                f0[6] = (__bf16)a1.z; f0[7] = (__bf16)a1.w;
                f1[0] = (__bf16)b0.x; f1[1] = (__bf16)b0.y;
                f1[2] = (__bf16)b0.z; f1[3] = (__bf16)b0.w;
                f1[4] = (__bf16)b1.x; f1[5] = (__bf16)b1.y;
                f1[6] = (__bf16)b1.z; f1[7] = (__bf16)b1.w;
                xf[st][0] = f0;
                xf[st][1] = f1;
            }
        }

        float m[TPW], s[TPW];
        #pragma unroll
        for (int st = 0; st < TPW; ++st) { m[st] = -INFINITY; s[st] = 0.0f; }

        #pragma unroll 2
        for (int ii = 0; ii < HC; ++ii) {
            const int kk = (ii + w) & (HC - 1);      // per-wave stagger
            float mah[TPW];
            #pragma unroll
            for (int st = 0; st < TPW; ++st) mah[st] = 0.0f;

            const char* gk = gbuf + kk * 8192;
            const float* ntk = &nt_lds[kk * NF];

            // rc 0,1: rows 0..31 of lower-tri G -> cols 32..63 are ZERO
            #pragma unroll
            for (int rc = 0; rc < 2; ++rc) {
                bf16x8 ga = *(const bf16x8*)(gk + offA[rc]);
                f32x4 ntv = *(const f32x4*)(ntk + rc * 16 + lg * 4);
                #pragma unroll
                for (int st = 0; st < TPW; ++st) {
                    f32x4 acc = ntv;
                    acc = __builtin_amdgcn_mfma_f32_16x16x32_bf16(ga, xf[st][0], acc, 0, 0, 0);
                    mah[st] = fmaf(acc[0], acc[0], mah[st]);
                    mah[st] = fmaf(acc[1], acc[1], mah[st]);
                    mah[st] = fmaf(acc[2], acc[2], mah[st]);
                    mah[st] = fmaf(acc[3], acc[3], mah[st]);
                }
            }
            // rc 2,3: full rows
            #pragma unroll
            for (int rc = 2; rc < 4; ++rc) {
                bf16x8 ga = *(const bf16x8*)(gk + offA[rc]);
                bf16x8 gb = *(const bf16x8*)(gk + offB[rc]);
                f32x4 ntv = *(const f32x4*)(ntk + rc * 16 + lg * 4);
                #pragma unroll
                for (int st = 0; st < TPW; ++st) {
                    f32x4 acc = ntv;
                    acc = __builtin_amdgcn_mfma_f32_16x16x32_bf16(ga, xf[st][0], acc, 0, 0, 0);
                    acc = __builtin_amdgcn_mfma_f32_16x16x32_bf16(gb, xf[st][1], acc, 0, 0, 0);
                    mah[st] = fmaf(acc[0], acc[0], mah[st]);
                    mah[st] = fmaf(acc[1], acc[1], mah[st]);
                    mah[st] = fmaf(acc[2], acc[2], mah[st]);
                    mah[st] = fmaf(acc[3], acc[3], mah[st]);
                }
            }

            float Ck = cc_lds[kk];
            #pragma unroll
            for (int st = 0; st < TPW; ++st) {
                float v = xor32_sum(xor16_sum(mah[st]));   // VALU-pipe reduce
                float wlp = fmaf(-0.5f, v, Ck);
                float mo = m[st];
                float mn = fmaxf(mo, wlp);
                s[st] = s[st] * __expf(mo - mn) + __expf(wlp - mn);
                m[st] = mn;
            }
        }

        // per-sample half-LSE -> global (lanes lg==0 hold the 16 cols)
        if (lg == 0) {
            float* dst = lseP + (size_t)half * 64 * nTiles + (size_t)tile * 64;
            #pragma unroll
            for (int st = 0; st < TPW; ++st) {
                long sid = base + st * 16 + l15;
                if (sid < (long)N)
                    dst[st * 16 + l15] = m[st] + __logf(s[st]);
            }
        }
    }
}

// ---------------------------------------------------------------------------
// Kernel 3: merge the two half-LSEs per sample (exact) + block sums.
// ---------------------------------------------------------------------------
__global__ __launch_bounds__(256) void gmm_partial(
    const float* __restrict__ lseP, int nTiles, int N,
    float* __restrict__ blockPartials)
{
    const float* h1 = lseP + (size_t)64 * nTiles;
    float acc = 0.0f;
    for (int sid = blockIdx.x * 256 + threadIdx.x; sid < N; sid += 256 * 256) {
        float a = lseP[sid], b = h1[sid];
        float M = fmaxf(a, b);
        acc += M + __logf(__expf(a - M) + __expf(b - M));
    }
    #pragma unroll
    for (int off = 1; off < 64; off <<= 1)
        acc += __shfl_xor(acc, off);
    __shared__ float sm[4];
    if ((threadIdx.x & 63) == 0) sm[threadIdx.x >> 6] = acc;
    __syncthreads();
    if (threadIdx.x == 0)
        blockPartials[blockIdx.x] = (sm[0] + sm[1]) + (sm[2] + sm[3]);
}

// ---------------------------------------------------------------------------
// Kernel 4: deterministic final reduction over block partials.
// ---------------------------------------------------------------------------
__global__ __launch_bounds__(256) void gmm_reduce(
    const float* __restrict__ partials, int n, float* __restrict__ out)
{
    float s = 0.0f;
    for (int i = threadIdx.x; i < n; i += 256)
        s += partials[i];
    #pragma unroll
    for (int off = 1; off < 64; off <<= 1)
        s += __shfl_xor(s, off);
    __shared__ float sm[4];
    const int wave = threadIdx.x >> 6;
    const int lane = threadIdx.x & 63;
    if (lane == 0) sm[wave] = s;
    __syncthreads();
    if (threadIdx.x == 0)
        out[0] = (sm[0] + sm[1]) + (sm[2] + sm[3]);
}

// ---------------------------------------------------------------------------
extern "C" void kernel_launch(void* const* d_in, const int* in_sizes, int n_in,
                              void* d_out, int out_size, void* d_ws, size_t ws_size,
                              hipStream_t stream)
{
    const float* data    = (const float*)d_in[0];
    const float* weights = (const float*)d_in[1];
    const float* means   = (const float*)d_in[2];
    const float* cov     = (const float*)d_in[3];

    const int N = in_sizes[0] / NF;

    const int nTiles     = (N + TPW * 16 - 1) / (TPW * 16);
    const int totalWaves = MAIN_GROUPS * MAIN_WAVES;

    char* ws = (char*)d_ws;
    __hip_bfloat16* g = (__hip_bfloat16*)ws;                    // 131072 B (swizzled)
    float* t          = (float*)(ws + 131072);                  // 4096 B
    float* Cc         = (float*)(ws + 131072 + 4096);           // 64 B
    float* lseP       = (float*)(ws + 131072 + 4096 + 64);      // 2*nTiles*64 floats
    float* blockPartials = lseP + (size_t)2 * nTiles * 64;      // 256 floats

    gmm_precompute<<<NC, 256, 0, stream>>>(cov, means, weights, g, t, Cc);
    gmm_main<<<MAIN_GROUPS * 2, 64 * MAIN_WAVES, 0, stream>>>(
        data, (const char*)g, t, Cc, lseP, nTiles, N, totalWaves);
    gmm_partial<<<256, 256, 0, stream>>>(lseP, nTiles, N, blockPartials);
    gmm_reduce<<<1, 256, 0, stream>>>(blockPartials, 256, (float*)d_out);
}

// Round 15
// 73.772 us; speedup vs baseline: 1.2011x; 1.2011x over previous
//
#include <hip/hip_runtime.h>
#include <hip/hip_bf16.h>
#include <math.h>

#define NF 64
#define NC 16
#define HC 8                           // comps per half-block
#define MAIN_GROUPS 256                // tile groups; blocks = 2*groups
#define MAIN_WAVES  13                 // 832 thr; 3328 tile-slots vs 3125 tiles
#define TPW 4                          // 16-sample subtiles per wave (64 samples)

typedef __bf16 bf16x8 __attribute__((ext_vector_type(8)));
typedef float f32x4 __attribute__((ext_vector_type(4)));
typedef unsigned int u32;

// async global->LDS, 16B/lane. LDS dest = wave-uniform base (HW adds lane*16).
__device__ __forceinline__ void stage16(const void* gsrc, void* ldst) {
    __builtin_amdgcn_global_load_lds(
        (const __attribute__((address_space(1))) u32*)gsrc,
        (__attribute__((address_space(3))) u32*)ldst,
        16, 0, 0);
}

// VALU-pipe cross-lane reductions (permlane swaps; not on the lgkm queue).
__device__ __forceinline__ float xor32_sum(float x) {
    float a = x, b = x;
    asm("v_permlane32_swap_b32 %0, %1" : "+v"(a), "+v"(b));
    return a + b;
}
__device__ __forceinline__ float xor16_sum(float x) {
    float a = x, b = x;
    asm("v_permlane16_swap_b32 %0, %1" : "+v"(a), "+v"(b));
    return a + b;
}

// ---------------------------------------------------------------------------
// Kernel 1 v8 (unchanged): 4-wave cooperative Cholesky + inverse, rolled
// phase loops (L1I-resident ~13KB). See round-8 notes.
// ---------------------------------------------------------------------------
__global__ __launch_bounds__(256) void gmm_precompute(
    const float* __restrict__ cov,
    const float* __restrict__ means,
    const float* __restrict__ weights,
    __hip_bfloat16* __restrict__ g,
    float* __restrict__ t,
    float* __restrict__ Cc)
{
    const int w = threadIdx.x >> 6;   // wave 0..3: rows [16w,16w+16)
    const int c = threadIdx.x & 63;   // lane owns column c
    const int k = blockIdx.x;

    __shared__ __align__(16) float LT[NF][68];   // LT[j][r] = L[r][j]
    __shared__ float Xs[NF][65];                 // Xs[i][c] = G[i][c]
    __shared__ __align__(16) float wb2[2][68];   // ping-pong published row
    __shared__ __align__(16) float gw2[2][68];   // ping-pong published G row

    float a_loc[16];
    {
        const float* src = cov + (long)k * NF * NF + (w * 16) * NF + c;
        #pragma unroll
        for (int r = 0; r < 16; ++r)
            a_loc[r] = src[r * NF];
    }

    float rsq_loc[16];
    float logdiag = 0.0f;

    #pragma unroll 1
    for (int q = 0; q < 4; ++q) {
        #pragma unroll
        for (int jj = 0; jj < 16; ++jj) {
            float* wb = wb2[jj & 1];
            if (w == q) wb[c] = a_loc[jj];       // publish trailing row j
            __syncthreads();
            const int j = q * 16 + jj;
            float ajc = wb[c];
            float d   = wb[j];
            float sq  = sqrtf(d);
            float rsq = __builtin_amdgcn_rcpf(sq);
            float rd  = __builtin_amdgcn_rcpf(d);
            logdiag += 0.5f * __logf(d);
            if (w == q) rsq_loc[jj] = rsq;
            LT[j][c] = ajc * rsq;
            float beta = ajc * rd;
            const float4* wv = (const float4*)(wb + w * 16);
            #pragma unroll
            for (int rr = 0; rr < 16; rr += 4) {
                float4 v = wv[rr >> 2];
                a_loc[rr]     = fmaf(-v.x, beta, a_loc[rr]);
                a_loc[rr + 1] = fmaf(-v.y, beta, a_loc[rr + 1]);
                a_loc[rr + 2] = fmaf(-v.z, beta, a_loc[rr + 2]);
                a_loc[rr + 3] = fmaf(-v.w, beta, a_loc[rr + 3]);
            }
        }
    }

    float s_loc[16];
    #pragma unroll
    for (int r = 0; r < 16; ++r)
        s_loc[r] = (w * 16 + r == c) ? 1.0f : 0.0f;

    #pragma unroll 1
    for (int q = 0; q < 4; ++q) {
        #pragma unroll
        for (int ii = 0; ii < 16; ++ii) {
            const int i = q * 16 + ii;
            float* gw = gw2[ii & 1];
            if (w == q) {
                float gv = s_loc[ii] * rsq_loc[ii];
                gw[c] = gv;
                Xs[i][c] = gv;
            }
            __syncthreads();
            float gc = gw[c];
            const float4* lv4 = (const float4*)(&LT[i][w * 16]);
            #pragma unroll
            for (int rr = 0; rr < 16; rr += 4) {
                float4 v = lv4[rr >> 2];
                s_loc[rr]     = fmaf(-v.x, gc, s_loc[rr]);
                s_loc[rr + 1] = fmaf(-v.y, gc, s_loc[rr + 1]);
                s_loc[rr + 2] = fmaf(-v.z, gc, s_loc[rr + 2]);
                s_loc[rr + 3] = fmaf(-v.w, gc, s_loc[rr + 3]);
            }
        }
    }
    __syncthreads();

    // g row c: chunks jb=2w,2w+1, XOR-swizzled (jb ^ (row&7))
    {
        __hip_bfloat16* grow = g + ((long)(k * NF + c)) * NF;
        #pragma unroll
        for (int h = 0; h < 2; ++h) {
            int jb = w * 2 + h;
            bf16x8 v;
            #pragma unroll
            for (int u = 0; u < 8; ++u)
                v[u] = (__bf16)Xs[c][jb * 8 + u];
            *(bf16x8*)(grow + ((jb ^ (c & 7)) * 8)) = v;
        }
    }

    if (w == 0) {
        const float* mu = means + k * NF;
        float a0 = 0.0f, a1 = 0.0f;
        #pragma unroll
        for (int j = 0; j < NF; j += 2) {
            a0 = fmaf(Xs[c][j],     mu[j],     a0);
            a1 = fmaf(Xs[c][j + 1], mu[j + 1], a1);
        }
        t[k * NF + c] = a0 + a1;
        if (c == 0)
            Cc[k] = __logf(weights[k]) - 0.5f * (float)NF * 1.8378770664093453f - logdiag;
    }
}

// ---------------------------------------------------------------------------
// Kernel 2 v15: component-split, repaired.
//  - PLAIN __launch_bounds__(832): v14's (832,7) forced a 36-VGPR class and
//    spilled 60MB; v13's natural codegen was 52 VGPR <= 64-class, which is
//    what 26 waves/CU (2 blocks) needs.
//  - XCD-paired halves: half = bid/256, grp = bid%256, so halves (g, g+256)
//    land on the SAME XCD ((g+256)%8 == g%8) and the second read of the
//    data tile hits that XCD's L2 instead of HBM.
//  64KB G + 2KB nt LDS -> 2 blocks/CU = 6.5 waves/SIMD (2x v13 TLP), same
//  per-CU DS/VALU/MFMA totals. Half-LSE written to lseP; merged exactly in
//  gmm_partial (logsumexp is associative).
// ---------------------------------------------------------------------------
__global__ __launch_bounds__(832) void gmm_main(
    const float* __restrict__ data,
    const char* __restrict__ gsw,         // swizzled bf16 G, [NC][8192 B]
    const float* __restrict__ t,
    const float* __restrict__ Cc,
    float* __restrict__ lseP,             // [2][nTiles*64] half-LSE
    int nTiles, int N, int totalWaves)
{
    __shared__ __align__(16) char gbuf[HC * 8192];   // 64 KiB
    __shared__ __align__(16) float nt_lds[HC * NF];  // 2 KiB
    __shared__ float cc_lds[HC];

    const int tidx = threadIdx.x;
    const int w    = tidx >> 6;
    const int lane = tidx & 63;
    const int l15  = lane & 15;
    const int lg   = lane >> 4;
    const int half = blockIdx.x / MAIN_GROUPS;   // 0 or 1; pair shares XCD
    const int grp  = blockIdx.x % MAIN_GROUPS;

    // waves 0..7 stage one comp each (half*8 + w)
    if (w < HC) {
        const char* src = gsw + (size_t)(half * HC + w) * 8192;
        char* dst = gbuf + (size_t)w * 8192;
        #pragma unroll
        for (int u = 0; u < 8; ++u)
            stage16(src + u * 1024 + lane * 16, dst + u * 1024);
    }
    for (int i = tidx; i < HC * NF; i += 64 * MAIN_WAVES)
        nt_lds[i] = -t[half * HC * NF + i];
    if (tidx < HC) cc_lds[tidx] = Cc[half * HC + tidx];

    const int gid = grp * MAIN_WAVES + w;

    // swizzled LDS byte offsets (static per lane)
    int offA[4], offB[4];
    #pragma unroll
    for (int rc = 0; rc < 4; ++rc) {
        int row = rc * 16 + l15;
        offA[rc] = row * 128 + ((lg       ^ (l15 & 7)) * 16);
        offB[rc] = row * 128 + (((lg + 4) ^ (l15 & 7)) * 16);
    }

    // first tile's x fragments (overlaps the staging flight)
    bf16x8 xf[TPW][2];
    if (gid < nTiles) {
        const long base = (long)gid * (TPW * 16);
        #pragma unroll
        for (int st = 0; st < TPW; ++st) {
            long row = base + st * 16 + l15;
            if (row > (long)N - 1) row = (long)N - 1;
            const float* xp = data + row * NF + lg * 8;
            float4 a0 = *(const float4*)(xp);
            float4 a1 = *(const float4*)(xp + 4);
            float4 b0 = *(const float4*)(xp + 32);
            float4 b1 = *(const float4*)(xp + 36);
            bf16x8 f0, f1;
            f0[0] = (__bf16)a0.x; f0[1] = (__bf16)a0.y;
            f0[2] = (__bf16)a0.z; f0[3] = (__bf16)a0.w;
            f0[4] = (__bf16)a1.x; f0[5] = (__bf16)a1.y;
            f0[6] = (__bf16)a1.z; f0[7] = (__bf16)a1.w;
            f1[0] = (__bf16)b0.x; f1[1] = (__bf16)b0.y;
            f1[2] = (__bf16)b0.z; f1[3] = (__bf16)b0.w;
            f1[4] = (__bf16)b1.x; f1[5] = (__bf16)b1.y;
            f1[6] = (__bf16)b1.z; f1[7] = (__bf16)b1.w;
            xf[st][0] = f0;
            xf[st][1] = f1;
        }
    }

    __syncthreads();   // G + t staged; only barrier in the kernel

    #pragma unroll 1
    for (int tile = gid; tile < nTiles; tile += totalWaves) {
        const long base = (long)tile * (TPW * 16);
        if (tile != gid) {     // grid-stride continuation (cold path)
            #pragma unroll
            for (int st = 0; st < TPW; ++st) {
                long row = base + st * 16 + l15;
                if (row > (long)N - 1) row = (long)N - 1;
                const float* xp = data + row * NF + lg * 8;
                float4 a0 = *(const float4*)(xp);
                float4 a1 = *(const float4*)(xp + 4);
                float4 b0 = *(const float4*)(xp + 32);
                float4 b1 = *(const float4*)(xp + 36);
                bf16x8 f0, f1;
                f0[0] = (__bf16)a0.x; f0[1] = (__bf16)a0.y;
                f0[2] = (__bf16)a0.z; f0[3] = (__bf16)a0.w;
                f0[4] = (__bf16)a1.x; f0[5] = (__bf16)a1.y;
                f0[6] = (__bf16)a1.z; f0[7] = (__bf16)a1.w;
                f1[0] = (__bf16)b0.x; f1[1] = (__bf16)b0.y;
                f1[2] = (__bf16)b0.z; f1[3] = (__bf16)b0.w;
                f1[4] = (__bf16)b1.x; f1[5] = (__bf16)b1.y;
                f1[6] = (__bf16)b1.z; f1[7] = (__bf16)b1.w;
                xf[st][0] = f0;
                xf[st][1] = f1;
            }
        }

        float m[TPW], s[TPW];
        #pragma unroll
        for (int st = 0; st < TPW; ++st) { m[st] = -INFINITY; s[st] = 0.0f; }

        #pragma unroll 2
        for (int ii = 0; ii < HC; ++ii) {
            const int kk = (ii + w) & (HC - 1);      // per-wave stagger
            float mah[TPW];
            #pragma unroll
            for (int st = 0; st < TPW; ++st) mah[st] = 0.0f;

            const char* gk = gbuf + kk * 8192;
            const float* ntk = &nt_lds[kk * NF];

            // rc 0,1: rows 0..31 of lower-tri G -> cols 32..63 are ZERO
            #pragma unroll
            for (int rc = 0; rc < 2; ++rc) {
                bf16x8 ga = *(const bf16x8*)(gk + offA[rc]);
                f32x4 ntv = *(const f32x4*)(ntk + rc * 16 + lg * 4);
                #pragma unroll
                for (int st = 0; st < TPW; ++st) {
                    f32x4 acc = ntv;
                    acc = __builtin_amdgcn_mfma_f32_16x16x32_bf16(ga, xf[st][0], acc, 0, 0, 0);
                    mah[st] = fmaf(acc[0], acc[0], mah[st]);
                    mah[st] = fmaf(acc[1], acc[1], mah[st]);
                    mah[st] = fmaf(acc[2], acc[2], mah[st]);
                    mah[st] = fmaf(acc[3], acc[3], mah[st]);
                }
            }
            // rc 2,3: full rows
            #pragma unroll
            for (int rc = 2; rc < 4; ++rc) {
                bf16x8 ga = *(const bf16x8*)(gk + offA[rc]);
                bf16x8 gb = *(const bf16x8*)(gk + offB[rc]);
                f32x4 ntv = *(const f32x4*)(ntk + rc * 16 + lg * 4);
                #pragma unroll
                for (int st = 0; st < TPW; ++st) {
                    f32x4 acc = ntv;
                    acc = __builtin_amdgcn_mfma_f32_16x16x32_bf16(ga, xf[st][0], acc, 0, 0, 0);
                    acc = __builtin_amdgcn_mfma_f32_16x16x32_bf16(gb, xf[st][1], acc, 0, 0, 0);
                    mah[st] = fmaf(acc[0], acc[0], mah[st]);
                    mah[st] = fmaf(acc[1], acc[1], mah[st]);
                    mah[st] = fmaf(acc[2], acc[2], mah[st]);
                    mah[st] = fmaf(acc[3], acc[3], mah[st]);
                }
            }

            float Ck = cc_lds[kk];
            #pragma unroll
            for (int st = 0; st < TPW; ++st) {
                float v = xor32_sum(xor16_sum(mah[st]));   // VALU-pipe reduce
                float wlp = fmaf(-0.5f, v, Ck);
                float mo = m[st];
                float mn = fmaxf(mo, wlp);
                s[st] = s[st] * __expf(mo - mn) + __expf(wlp - mn);
                m[st] = mn;
            }
        }

        // per-sample half-LSE -> global (lanes lg==0 hold the 16 cols)
        if (lg == 0) {
            float* dst = lseP + (size_t)half * 64 * nTiles + (size_t)tile * 64;
            #pragma unroll
            for (int st = 0; st < TPW; ++st) {
                long sid = base + st * 16 + l15;
                if (sid < (long)N)
                    dst[st * 16 + l15] = m[st] + __logf(s[st]);
            }
        }
    }
}

// ---------------------------------------------------------------------------
// Kernel 3: merge the two half-LSEs per sample (exact) + block sums.
// ---------------------------------------------------------------------------
__global__ __launch_bounds__(256) void gmm_partial(
    const float* __restrict__ lseP, int nTiles, int N,
    float* __restrict__ blockPartials)
{
    const float* h1 = lseP + (size_t)64 * nTiles;
    float acc = 0.0f;
    for (int sid = blockIdx.x * 256 + threadIdx.x; sid < N; sid += 256 * 256) {
        float a = lseP[sid], b = h1[sid];
        float M = fmaxf(a, b);
        acc += M + __logf(__expf(a - M) + __expf(b - M));
    }
    #pragma unroll
    for (int off = 1; off < 64; off <<= 1)
        acc += __shfl_xor(acc, off);
    __shared__ float sm[4];
    if ((threadIdx.x & 63) == 0) sm[threadIdx.x >> 6] = acc;
    __syncthreads();
    if (threadIdx.x == 0)
        blockPartials[blockIdx.x] = (sm[0] + sm[1]) + (sm[2] + sm[3]);
}

// ---------------------------------------------------------------------------
// Kernel 4: deterministic final reduction over block partials.
// ---------------------------------------------------------------------------
__global__ __launch_bounds__(256) void gmm_reduce(
    const float* __restrict__ partials, int n, float* __restrict__ out)
{
    float s = 0.0f;
    for (int i = threadIdx.x; i < n; i += 256)
        s += partials[i];
    #pragma unroll
    for (int off = 1; off < 64; off <<= 1)
        s += __shfl_xor(s, off);
    __shared__ float sm[4];
    const int wave = threadIdx.x >> 6;
    const int lane = threadIdx.x & 63;
    if (lane == 0) sm[wave] = s;
    __syncthreads();
    if (threadIdx.x == 0)
        out[0] = (sm[0] + sm[1]) + (sm[2] + sm[3]);
}

// ---------------------------------------------------------------------------
extern "C" void kernel_launch(void* const* d_in, const int* in_sizes, int n_in,
                              void* d_out, int out_size, void* d_ws, size_t ws_size,
                              hipStream_t stream)
{
    const float* data    = (const float*)d_in[0];
    const float* weights = (const float*)d_in[1];
    const float* means   = (const float*)d_in[2];
    const float* cov     = (const float*)d_in[3];

    const int N = in_sizes[0] / NF;

    const int nTiles     = (N + TPW * 16 - 1) / (TPW * 16);
    const int totalWaves = MAIN_GROUPS * MAIN_WAVES;

    char* ws = (char*)d_ws;
    __hip_bfloat16* g = (__hip_bfloat16*)ws;                    // 131072 B (swizzled)
    float* t          = (float*)(ws + 131072);                  // 4096 B
    float* Cc         = (float*)(ws + 131072 + 4096);           // 64 B
    float* lseP       = (float*)(ws + 131072 + 4096 + 64);      // 2*nTiles*64 floats
    float* blockPartials = lseP + (size_t)2 * nTiles * 64;      // 256 floats

    gmm_precompute<<<NC, 256, 0, stream>>>(cov, means, weights, g, t, Cc);
    gmm_main<<<MAIN_GROUPS * 2, 64 * MAIN_WAVES, 0, stream>>>(
        data, (const char*)g, t, Cc, lseP, nTiles, N, totalWaves);
    gmm_partial<<<256, 256, 0, stream>>>(lseP, nTiles, N, blockPartials);
    gmm_reduce<<<1, 256, 0, stream>>>(blockPartials, 256, (float*)d_out);
}

// Round 16
// 65.040 us; speedup vs baseline: 1.3623x; 1.1343x over previous
//
#include <hip/hip_runtime.h>
#include <hip/hip_bf16.h>
#include <math.h>

#define NF 64
#define NC 16
#define MAIN_BLOCKS 256
#define MAIN_WAVES  13                 // 832 thr; 3328 waves vs 3125 tiles, all CUs
#define TPW 4                          // 16-sample subtiles per wave (64 samples)

typedef __bf16 bf16x8 __attribute__((ext_vector_type(8)));
typedef float f32x4 __attribute__((ext_vector_type(4)));
typedef unsigned int u32;

// async global->LDS, 16B/lane. LDS dest = wave-uniform base (HW adds lane*16).
__device__ __forceinline__ void stage16(const void* gsrc, void* ldst) {
    __builtin_amdgcn_global_load_lds(
        (const __attribute__((address_space(1))) u32*)gsrc,
        (__attribute__((address_space(3))) u32*)ldst,
        16, 0, 0);
}

// ---------------------------------------------------------------------------
// Kernel 1 v8 (unchanged): 4-wave cooperative Cholesky + inverse, rolled
// phase loops (L1I-resident ~13KB). See round-8 notes.
// ---------------------------------------------------------------------------
__global__ __launch_bounds__(256) void gmm_precompute(
    const float* __restrict__ cov,
    const float* __restrict__ means,
    const float* __restrict__ weights,
    __hip_bfloat16* __restrict__ g,
    float* __restrict__ t,
    float* __restrict__ Cc)
{
    const int w = threadIdx.x >> 6;   // wave 0..3: rows [16w,16w+16)
    const int c = threadIdx.x & 63;   // lane owns column c
    const int k = blockIdx.x;

    __shared__ __align__(16) float LT[NF][68];   // LT[j][r] = L[r][j]
    __shared__ float Xs[NF][65];                 // Xs[i][c] = G[i][c]
    __shared__ __align__(16) float wb2[2][68];   // ping-pong published row
    __shared__ __align__(16) float gw2[2][68];   // ping-pong published G row

    float a_loc[16];
    {
        const float* src = cov + (long)k * NF * NF + (w * 16) * NF + c;
        #pragma unroll
        for (int r = 0; r < 16; ++r)
            a_loc[r] = src[r * NF];
    }

    float rsq_loc[16];
    float logdiag = 0.0f;

    #pragma unroll 1
    for (int q = 0; q < 4; ++q) {
        #pragma unroll
        for (int jj = 0; jj < 16; ++jj) {
            float* wb = wb2[jj & 1];
            if (w == q) wb[c] = a_loc[jj];       // publish trailing row j
            __syncthreads();
            const int j = q * 16 + jj;
            float ajc = wb[c];
            float d   = wb[j];
            float sq  = sqrtf(d);
            float rsq = __builtin_amdgcn_rcpf(sq);
            float rd  = __builtin_amdgcn_rcpf(d);
            logdiag += 0.5f * __logf(d);
            if (w == q) rsq_loc[jj] = rsq;
            LT[j][c] = ajc * rsq;
            float beta = ajc * rd;
            const float4* wv = (const float4*)(wb + w * 16);
            #pragma unroll
            for (int rr = 0; rr < 16; rr += 4) {
                float4 v = wv[rr >> 2];
                a_loc[rr]     = fmaf(-v.x, beta, a_loc[rr]);
                a_loc[rr + 1] = fmaf(-v.y, beta, a_loc[rr + 1]);
                a_loc[rr + 2] = fmaf(-v.z, beta, a_loc[rr + 2]);
                a_loc[rr + 3] = fmaf(-v.w, beta, a_loc[rr + 3]);
            }
        }
    }

    float s_loc[16];
    #pragma unroll
    for (int r = 0; r < 16; ++r)
        s_loc[r] = (w * 16 + r == c) ? 1.0f : 0.0f;

    #pragma unroll 1
    for (int q = 0; q < 4; ++q) {
        #pragma unroll
        for (int ii = 0; ii < 16; ++ii) {
            const int i = q * 16 + ii;
            float* gw = gw2[ii & 1];
            if (w == q) {
                float gv = s_loc[ii] * rsq_loc[ii];
                gw[c] = gv;
                Xs[i][c] = gv;
            }
            __syncthreads();
            float gc = gw[c];
            const float4* lv4 = (const float4*)(&LT[i][w * 16]);
            #pragma unroll
            for (int rr = 0; rr < 16; rr += 4) {
                float4 v = lv4[rr >> 2];
                s_loc[rr]     = fmaf(-v.x, gc, s_loc[rr]);
                s_loc[rr + 1] = fmaf(-v.y, gc, s_loc[rr + 1]);
                s_loc[rr + 2] = fmaf(-v.z, gc, s_loc[rr + 2]);
                s_loc[rr + 3] = fmaf(-v.w, gc, s_loc[rr + 3]);
            }
        }
    }
    __syncthreads();

    // g row c: chunks jb=2w,2w+1, XOR-swizzled (jb ^ (row&7))
    {
        __hip_bfloat16* grow = g + ((long)(k * NF + c)) * NF;
        #pragma unroll
        for (int h = 0; h < 2; ++h) {
            int jb = w * 2 + h;
            bf16x8 v;
            #pragma unroll
            for (int u = 0; u < 8; ++u)
                v[u] = (__bf16)Xs[c][jb * 8 + u];
            *(bf16x8*)(grow + ((jb ^ (c & 7)) * 8)) = v;
        }
    }

    if (w == 0) {
        const float* mu = means + k * NF;
        float a0 = 0.0f, a1 = 0.0f;
        #pragma unroll
        for (int j = 0; j < NF; j += 2) {
            a0 = fmaf(Xs[c][j],     mu[j],     a0);
            a1 = fmaf(Xs[c][j + 1], mu[j + 1], a1);
        }
        t[k * NF + c] = a0 + a1;
        if (c == 0)
            Cc[k] = __logf(weights[k]) - 0.5f * (float)NF * 1.8378770664093453f - logdiag;
    }
}

// ---------------------------------------------------------------------------
// Kernel 2 v16: v12 structure (best measured: 16 comps/block, 13 waves,
// 0-conflict swizzle, triangular skip, stagger, one barrier) + DEFER-MAX
// logsumexp (T13): per comp, one wave-uniform __any(dmax>60) test; common
// path is s += exp(wlp-m) (1 exp, no rescale). Exact: rescale taken whenever
// any lane needs it; exp(60)*16 well within fp32 range. First comp flows
// through the rescale path naturally (s=0, m=-inf).
// ---------------------------------------------------------------------------
__global__ __launch_bounds__(832) void gmm_main(
    const float* __restrict__ data,
    const char* __restrict__ gsw,         // swizzled bf16 G, [NC][8192 B]
    const float* __restrict__ t,
    const float* __restrict__ Cc,
    float* __restrict__ partials,
    int nTiles, int N, int totalWaves)
{
    __shared__ __align__(16) char gbuf[NC * 8192];   // 128 KiB
    __shared__ __align__(16) float nt_lds[NC * NF];  // negated t
    __shared__ float cc_lds[NC];

    const int tidx = threadIdx.x;
    const int w    = tidx >> 6;
    const int lane = tidx & 63;
    const int l15  = lane & 15;
    const int lg   = lane >> 4;

    // stage G: wave w covers comps {w, w+13} (<16)
    for (int i = w; i < NC; i += MAIN_WAVES) {
        const char* src = gsw + (size_t)i * 8192;
        char* dst = gbuf + (size_t)i * 8192;
        #pragma unroll
        for (int u = 0; u < 8; ++u)
            stage16(src + u * 1024 + lane * 16, dst + u * 1024);
    }

    for (int i = tidx; i < NC * NF; i += 64 * MAIN_WAVES) nt_lds[i] = -t[i];
    if (tidx < NC) cc_lds[tidx] = Cc[tidx];

    const int gid = blockIdx.x * MAIN_WAVES + w;

    // swizzled LDS byte offsets (static per lane)
    int offA[4], offB[4];
    #pragma unroll
    for (int rc = 0; rc < 4; ++rc) {
        int row = rc * 16 + l15;
        offA[rc] = row * 128 + ((lg       ^ (l15 & 7)) * 16);
        offB[rc] = row * 128 + (((lg + 4) ^ (l15 & 7)) * 16);
    }

    // first tile's x fragments (overlaps the staging flight)
    bf16x8 xf[TPW][2];
    if (gid < nTiles) {
        const long base = (long)gid * (TPW * 16);
        #pragma unroll
        for (int st = 0; st < TPW; ++st) {
            long row = base + st * 16 + l15;
            if (row > (long)N - 1) row = (long)N - 1;
            const float* xp = data + row * NF + lg * 8;
            float4 a0 = *(const float4*)(xp);
            float4 a1 = *(const float4*)(xp + 4);
            float4 b0 = *(const float4*)(xp + 32);
            float4 b1 = *(const float4*)(xp + 36);
            bf16x8 f0, f1;
            f0[0] = (__bf16)a0.x; f0[1] = (__bf16)a0.y;
            f0[2] = (__bf16)a0.z; f0[3] = (__bf16)a0.w;
            f0[4] = (__bf16)a1.x; f0[5] = (__bf16)a1.y;
            f0[6] = (__bf16)a1.z; f0[7] = (__bf16)a1.w;
            f1[0] = (__bf16)b0.x; f1[1] = (__bf16)b0.y;
            f1[2] = (__bf16)b0.z; f1[3] = (__bf16)b0.w;
            f1[4] = (__bf16)b1.x; f1[5] = (__bf16)b1.y;
            f1[6] = (__bf16)b1.z; f1[7] = (__bf16)b1.w;
            xf[st][0] = f0;
            xf[st][1] = f1;
        }
    }

    __syncthreads();   // G + t staged; only barrier in the kernel

    float wavePartial = 0.0f;

    #pragma unroll 1
    for (int tile = gid; tile < nTiles; tile += totalWaves) {
        const long base = (long)tile * (TPW * 16);
        if (tile != gid) {     // grid-stride continuation (cold path)
            #pragma unroll
            for (int st = 0; st < TPW; ++st) {
                long row = base + st * 16 + l15;
                if (row > (long)N - 1) row = (long)N - 1;
                const float* xp = data + row * NF + lg * 8;
                float4 a0 = *(const float4*)(xp);
                float4 a1 = *(const float4*)(xp + 4);
                float4 b0 = *(const float4*)(xp + 32);
                float4 b1 = *(const float4*)(xp + 36);
                bf16x8 f0, f1;
                f0[0] = (__bf16)a0.x; f0[1] = (__bf16)a0.y;
                f0[2] = (__bf16)a0.z; f0[3] = (__bf16)a0.w;
                f0[4] = (__bf16)a1.x; f0[5] = (__bf16)a1.y;
                f0[6] = (__bf16)a1.z; f0[7] = (__bf16)a1.w;
                f1[0] = (__bf16)b0.x; f1[1] = (__bf16)b0.y;
                f1[2] = (__bf16)b0.z; f1[3] = (__bf16)b0.w;
                f1[4] = (__bf16)b1.x; f1[5] = (__bf16)b1.y;
                f1[6] = (__bf16)b1.z; f1[7] = (__bf16)b1.w;
                xf[st][0] = f0;
                xf[st][1] = f1;
            }
        }

        float m[TPW], s[TPW];
        #pragma unroll
        for (int st = 0; st < TPW; ++st) { m[st] = -INFINITY; s[st] = 0.0f; }

        #pragma unroll 2
        for (int ii = 0; ii < NC; ++ii) {
            const int kk = (ii + w) & (NC - 1);      // per-wave stagger
            float mah[TPW];
            #pragma unroll
            for (int st = 0; st < TPW; ++st) mah[st] = 0.0f;

            const char* gk = gbuf + kk * 8192;
            const float* ntk = &nt_lds[kk * NF];

            // rc 0,1: rows 0..31 of lower-tri G -> cols 32..63 are ZERO
            #pragma unroll
            for (int rc = 0; rc < 2; ++rc) {
                bf16x8 ga = *(const bf16x8*)(gk + offA[rc]);
                f32x4 ntv = *(const f32x4*)(ntk + rc * 16 + lg * 4);
                #pragma unroll
                for (int st = 0; st < TPW; ++st) {
                    f32x4 acc = ntv;
                    acc = __builtin_amdgcn_mfma_f32_16x16x32_bf16(ga, xf[st][0], acc, 0, 0, 0);
                    mah[st] = fmaf(acc[0], acc[0], mah[st]);
                    mah[st] = fmaf(acc[1], acc[1], mah[st]);
                    mah[st] = fmaf(acc[2], acc[2], mah[st]);
                    mah[st] = fmaf(acc[3], acc[3], mah[st]);
                }
            }
            // rc 2,3: full rows
            #pragma unroll
            for (int rc = 2; rc < 4; ++rc) {
                bf16x8 ga = *(const bf16x8*)(gk + offA[rc]);
                bf16x8 gb = *(const bf16x8*)(gk + offB[rc]);
                f32x4 ntv = *(const f32x4*)(ntk + rc * 16 + lg * 4);
                #pragma unroll
                for (int st = 0; st < TPW; ++st) {
                    f32x4 acc = ntv;
                    acc = __builtin_amdgcn_mfma_f32_16x16x32_bf16(ga, xf[st][0], acc, 0, 0, 0);
                    acc = __builtin_amdgcn_mfma_f32_16x16x32_bf16(gb, xf[st][1], acc, 0, 0, 0);
                    mah[st] = fmaf(acc[0], acc[0], mah[st]);
                    mah[st] = fmaf(acc[1], acc[1], mah[st]);
                    mah[st] = fmaf(acc[2], acc[2], mah[st]);
                    mah[st] = fmaf(acc[3], acc[3], mah[st]);
                }
            }

            // ---- defer-max logsumexp ----
            float Ck = cc_lds[kk];
            float wlp[TPW];
            float dmax = -INFINITY;
            #pragma unroll
            for (int st = 0; st < TPW; ++st) {
                float v = mah[st];
                v += __shfl_xor(v, 16);
                v += __shfl_xor(v, 32);          // all lanes hold full maha
                wlp[st] = fmaf(-0.5f, v, Ck);
                dmax = fmaxf(dmax, wlp[st] - m[st]);
            }
            if (__any(dmax > 60.0f)) {           // rare after first comp
                #pragma unroll
                for (int st = 0; st < TPW; ++st) {
                    float mn = fmaxf(m[st], wlp[st]);
                    s[st] = s[st] * __expf(m[st] - mn) + __expf(wlp[st] - mn);
                    m[st] = mn;
                }
            } else {                             // common: 1 exp + 1 add
                #pragma unroll
                for (int st = 0; st < TPW; ++st)
                    s[st] += __expf(wlp[st] - m[st]);
            }
        }

        if (lg == 0) {
            #pragma unroll
            for (int st = 0; st < TPW; ++st) {
                long sid = base + st * 16 + l15;
                if (sid < (long)N)
                    wavePartial += m[st] + __logf(s[st]);
            }
        }
    }

    #pragma unroll
    for (int off = 1; off < 64; off <<= 1)
        wavePartial += __shfl_xor(wavePartial, off);
    if (lane == 0)
        partials[gid] = wavePartial;
}

// ---------------------------------------------------------------------------
// Kernel 3: deterministic final reduction over per-wave partials.
// ---------------------------------------------------------------------------
__global__ __launch_bounds__(256) void gmm_reduce(
    const float* __restrict__ partials, int n, float* __restrict__ out)
{
    float s = 0.0f;
    for (int i = threadIdx.x; i < n; i += 256)
        s += partials[i];
    #pragma unroll
    for (int off = 1; off < 64; off <<= 1)
        s += __shfl_xor(s, off);
    __shared__ float sm[4];
    const int wave = threadIdx.x >> 6;
    const int lane = threadIdx.x & 63;
    if (lane == 0) sm[wave] = s;
    __syncthreads();
    if (threadIdx.x == 0)
        out[0] = (sm[0] + sm[1]) + (sm[2] + sm[3]);
}

// ---------------------------------------------------------------------------
extern "C" void kernel_launch(void* const* d_in, const int* in_sizes, int n_in,
                              void* d_out, int out_size, void* d_ws, size_t ws_size,
                              hipStream_t stream)
{
    const float* data    = (const float*)d_in[0];
    const float* weights = (const float*)d_in[1];
    const float* means   = (const float*)d_in[2];
    const float* cov     = (const float*)d_in[3];

    const int N = in_sizes[0] / NF;

    char* ws = (char*)d_ws;
    __hip_bfloat16* g = (__hip_bfloat16*)ws;                    // 131072 B (swizzled)
    float* t          = (float*)(ws + 131072);                  // 4096 B
    float* Cc         = (float*)(ws + 131072 + 4096);           // 64 B
    float* partials   = (float*)(ws + 131072 + 4096 + 64);      // totalWaves * 4 B

    const int nTiles     = (N + TPW * 16 - 1) / (TPW * 16);
    const int totalWaves = MAIN_BLOCKS * MAIN_WAVES;

    gmm_precompute<<<NC, 256, 0, stream>>>(cov, means, weights, g, t, Cc);
    gmm_main<<<MAIN_BLOCKS, 64 * MAIN_WAVES, 0, stream>>>(
        data, (const char*)g, t, Cc, partials, nTiles, N, totalWaves);
    gmm_reduce<<<1, 256, 0, stream>>>(partials, totalWaves, (float*)d_out);
}